// Round 1
// baseline (2685.110 us; speedup 1.0000x reference)
//
#include <hip/hip_runtime.h>

// LSTMClassifier: 2-layer LSTM (H=64, T=512, B=2048, D_in=1) + FC(64->3).
// Strategy: fused single kernel, wave-autonomous recurrence.
//   - 256 blocks x 256 threads (4 waves). Block = 8 batch elems, wave = 2.
//   - lane = hidden unit j; lane j owns gate rows {j, 64+j, 128+j, 192+j}
//     = (i,f,g,o)_j  ->  c/h update is lane-local.
//   - Weights staged to LDS once as fp16 (range +-0.125, rel err 2^-11),
//     rows padded (68 / 132) so per-lane row gather hits the 4-cyc floor.
//   - h state round-trips through a small per-wave LDS buffer (broadcast
//     b128 reads). No __syncthreads in the time loop.

typedef _Float16 half4_t __attribute__((ext_vector_type(4)));
typedef float    float4_t __attribute__((ext_vector_type(4)));

#define TSTEPS 512
#define W0P 68            // padded row pitch (f16 elems) for w_hh0 [256][64]
#define W1P 132           // padded row pitch for [w_ih1 | w_hh1]  [256][128]

__device__ __forceinline__ float sigf(float z) {
    return 1.0f / (1.0f + __expf(-z));
}
__device__ __forceinline__ float tanh_fast(float z) {
    return 2.0f / (1.0f + __expf(-2.0f * z)) - 1.0f;
}

extern "C" __global__ __launch_bounds__(256)
void lstm2_fused(const float* __restrict__ x,
                 const float* __restrict__ w_ih0, const float* __restrict__ w_hh0,
                 const float* __restrict__ b_ih0, const float* __restrict__ b_hh0,
                 const float* __restrict__ w_ih1, const float* __restrict__ w_hh1,
                 const float* __restrict__ b_ih1, const float* __restrict__ b_hh1,
                 const float* __restrict__ w_fc,  const float* __restrict__ b_fc,
                 float* __restrict__ out)
{
    __shared__ _Float16 w0s[256 * W0P];      // 34,816 B
    __shared__ _Float16 w1s[256 * W1P];      // 67,584 B
    __shared__ float    hbuf[4][2][128];     // 4,096 B  [wave][batch][h0|h1]

    const int tid = threadIdx.x;

    // ---- stage weights (fp32 global -> fp16 LDS), coalesced ----
    for (int e = tid; e < 256 * 64; e += 256) {
        const int g = e >> 6, k = e & 63;
        w0s[g * W0P + k]      = (_Float16)w_hh0[e];
        w1s[g * W1P + k]      = (_Float16)w_ih1[e];   // cols 0..63  : h0 weights
        w1s[g * W1P + 64 + k] = (_Float16)w_hh1[e];   // cols 64..127: h1 weights
    }

    const int wv = tid >> 6;     // wave in block
    const int j  = tid & 63;     // hidden unit

    hbuf[wv][0][j] = 0.0f; hbuf[wv][0][64 + j] = 0.0f;
    hbuf[wv][1][j] = 0.0f; hbuf[wv][1][64 + j] = 0.0f;

    // per-lane constants: input-proj weight (D_in=1) and fused biases
    float wi0[4], bs0[4], bs1[4];
    #pragma unroll
    for (int q = 0; q < 4; ++q) {
        const int g = q * 64 + j;
        wi0[q] = w_ih0[g];
        bs0[q] = b_ih0[g] + b_hh0[g];
        bs1[q] = b_ih1[g] + b_hh1[g];
    }

    const int b0 = blockIdx.x * 8 + wv * 2;   // this wave's two batch rows

    float c0[2] = {0.f, 0.f}, c1[2] = {0.f, 0.f}, h1r[2] = {0.f, 0.f};

    __syncthreads();   // weights visible to all waves

    const float* xp0 = x + (long)b0 * TSTEPS;
    const float* xp1 = x + (long)(b0 + 1) * TSTEPS;

    for (int t = 0; t < TSTEPS; ++t) {
        // issue x loads early; consumed only in the layer-0 epilogue
        const float xv0 = xp0[t];
        const float xv1 = xp1[t];

        // ---------------- layer 0: gates = W_hh0 * h0 ----------------
        float a0[4][2];
        #pragma unroll
        for (int q = 0; q < 4; ++q) { a0[q][0] = bs0[q]; a0[q][1] = bs0[q]; }

        #pragma unroll 4
        for (int kb = 0; kb < 16; ++kb) {
            const float4_t ha = *(const float4_t*)&hbuf[wv][0][kb * 4];
            const float4_t hb = *(const float4_t*)&hbuf[wv][1][kb * 4];
            #pragma unroll
            for (int q = 0; q < 4; ++q) {
                const half4_t w4 = *(const half4_t*)&w0s[(q * 64 + j) * W0P + kb * 4];
                #pragma unroll
                for (int i = 0; i < 4; ++i) {
                    const float wf = (float)w4[i];
                    a0[q][0] = fmaf(wf, ha[i], a0[q][0]);
                    a0[q][1] = fmaf(wf, hb[i], a0[q][1]);
                }
            }
        }

        // epilogue: fold x*w_ih0, activations, c/h update (lane-local)
        float h0n[2];
        {
            float zi = a0[0][0] + xv0 * wi0[0];
            float zf = a0[1][0] + xv0 * wi0[1];
            float zg = a0[2][0] + xv0 * wi0[2];
            float zo = a0[3][0] + xv0 * wi0[3];
            c0[0] = sigf(zf) * c0[0] + sigf(zi) * tanh_fast(zg);
            h0n[0] = sigf(zo) * tanh_fast(c0[0]);
            zi = a0[0][1] + xv1 * wi0[0];
            zf = a0[1][1] + xv1 * wi0[1];
            zg = a0[2][1] + xv1 * wi0[2];
            zo = a0[3][1] + xv1 * wi0[3];
            c0[1] = sigf(zf) * c0[1] + sigf(zi) * tanh_fast(zg);
            h0n[1] = sigf(zo) * tanh_fast(c0[1]);
        }
        hbuf[wv][0][j] = h0n[0];     // h0(t) -> k = 0..63 slot
        hbuf[wv][1][j] = h0n[1];

        // ------------- layer 1: gates = W1 * [h0(t); h1(t-1)] -------------
        float a1[4][2];
        #pragma unroll
        for (int q = 0; q < 4; ++q) { a1[q][0] = bs1[q]; a1[q][1] = bs1[q]; }

        #pragma unroll 4
        for (int kb = 0; kb < 32; ++kb) {
            const float4_t ha = *(const float4_t*)&hbuf[wv][0][kb * 4];
            const float4_t hb = *(const float4_t*)&hbuf[wv][1][kb * 4];
            #pragma unroll
            for (int q = 0; q < 4; ++q) {
                const half4_t w4 = *(const half4_t*)&w1s[(q * 64 + j) * W1P + kb * 4];
                #pragma unroll
                for (int i = 0; i < 4; ++i) {
                    const float wf = (float)w4[i];
                    a1[q][0] = fmaf(wf, ha[i], a1[q][0]);
                    a1[q][1] = fmaf(wf, hb[i], a1[q][1]);
                }
            }
        }

        #pragma unroll
        for (int b = 0; b < 2; ++b) {
            const float zi = a1[0][b], zf = a1[1][b], zg = a1[2][b], zo = a1[3][b];
            c1[b] = sigf(zf) * c1[b] + sigf(zi) * tanh_fast(zg);
            h1r[b] = sigf(zo) * tanh_fast(c1[b]);
        }
        hbuf[wv][0][64 + j] = h1r[0];   // h1(t) -> k = 64..127 slot
        hbuf[wv][1][64 + j] = h1r[1];
    }

    // ---------------- FC head: out = h1 @ w_fc^T + b_fc ----------------
    const float wfc0 = w_fc[j], wfc1 = w_fc[64 + j], wfc2 = w_fc[128 + j];
    #pragma unroll
    for (int b = 0; b < 2; ++b) {
        float p0 = h1r[b] * wfc0;
        float p1 = h1r[b] * wfc1;
        float p2 = h1r[b] * wfc2;
        #pragma unroll
        for (int off = 32; off > 0; off >>= 1) {
            p0 += __shfl_down(p0, off);
            p1 += __shfl_down(p1, off);
            p2 += __shfl_down(p2, off);
        }
        if (j == 0) {
            float* o = out + (long)(b0 + b) * 3;
            o[0] = p0 + b_fc[0];
            o[1] = p1 + b_fc[1];
            o[2] = p2 + b_fc[2];
        }
    }
}

extern "C" void kernel_launch(void* const* d_in, const int* in_sizes, int n_in,
                              void* d_out, int out_size, void* d_ws, size_t ws_size,
                              hipStream_t stream) {
    const float* xx     = (const float*)d_in[0];
    const float* w_ih0  = (const float*)d_in[1];
    const float* w_hh0  = (const float*)d_in[2];
    const float* b_ih0  = (const float*)d_in[3];
    const float* b_hh0  = (const float*)d_in[4];
    const float* w_ih1  = (const float*)d_in[5];
    const float* w_hh1  = (const float*)d_in[6];
    const float* b_ih1  = (const float*)d_in[7];
    const float* b_hh1  = (const float*)d_in[8];
    const float* w_fc   = (const float*)d_in[9];
    const float* b_fc   = (const float*)d_in[10];
    float* out = (float*)d_out;

    lstm2_fused<<<dim3(256), dim3(256), 0, stream>>>(
        xx, w_ih0, w_hh0, b_ih0, b_hh0,
        w_ih1, w_hh1, b_ih1, b_hh1, w_fc, b_fc, out);
}

// Round 2
// 1460.306 us; speedup vs baseline: 1.8387x; 1.8387x over previous
//
#include <hip/hip_runtime.h>

// LSTMClassifier: 2-layer LSTM (H=64, T=512, B=2048, D_in=1) + FC(64->3).
// Round 1: v_dot2_f32_f16 path. Weights f16 in LDS (pitch-68/132 rows,
// measured conflict-free gather); h state stored f16 in LDS, read as packed
// half2; all accumulation fp32 via __builtin_amdgcn_fdot2.
//   - 256 blocks x 256 threads (4 waves), 1 block/CU, wave = 2 batch rows.
//   - lane j owns gate rows {j, 64+j, 128+j, 192+j} -> lane-local c/h update.
//   - No __syncthreads in the time loop (hbuf is wave-private).

typedef _Float16 half2_t __attribute__((ext_vector_type(2)));
struct h2x2 { half2_t a, b; };             // 8 B  (ds_read_b64)
struct h2x4 { half2_t a, b, c, d; };       // 16 B (ds_read_b128, uniform)

#define TSTEPS 512
#define W0P 68            // padded row pitch (f16 elems) for w_hh0 [256][64]
#define W1P 132           // padded row pitch for [w_ih1 | w_hh1]  [256][128]

__device__ __forceinline__ float fdot2(half2_t a, half2_t b, float c) {
#if __has_builtin(__builtin_amdgcn_fdot2)
    return __builtin_amdgcn_fdot2(a, b, c, false);
#else
    return fmaf((float)a[0], (float)b[0], fmaf((float)a[1], (float)b[1], c));
#endif
}

__device__ __forceinline__ float sigf(float z) {
    return 1.0f / (1.0f + __expf(-z));
}
__device__ __forceinline__ float tanh_fast(float z) {
    return 2.0f / (1.0f + __expf(-2.0f * z)) - 1.0f;
}

extern "C" __global__ __launch_bounds__(256)
void lstm2_fused(const float* __restrict__ x,
                 const float* __restrict__ w_ih0, const float* __restrict__ w_hh0,
                 const float* __restrict__ b_ih0, const float* __restrict__ b_hh0,
                 const float* __restrict__ w_ih1, const float* __restrict__ w_hh1,
                 const float* __restrict__ b_ih1, const float* __restrict__ b_hh1,
                 const float* __restrict__ w_fc,  const float* __restrict__ b_fc,
                 float* __restrict__ out)
{
    __shared__ _Float16 w0s[256 * W0P];      // 34,816 B
    __shared__ _Float16 w1s[256 * W1P];      // 67,584 B
    __shared__ _Float16 hbuf[4][2][128];     //  2,048 B  [wave][batch][h0|h1]

    const int tid = threadIdx.x;

    // ---- stage weights (fp32 global -> f16 LDS), coalesced ----
    for (int e = tid; e < 256 * 64; e += 256) {
        const int g = e >> 6, k = e & 63;
        w0s[g * W0P + k]      = (_Float16)w_hh0[e];
        w1s[g * W1P + k]      = (_Float16)w_ih1[e];   // cols 0..63  : h0
        w1s[g * W1P + 64 + k] = (_Float16)w_hh1[e];   // cols 64..127: h1
    }

    const int wv = tid >> 6;     // wave in block
    const int j  = tid & 63;     // hidden unit

    hbuf[wv][0][j] = (_Float16)0.f; hbuf[wv][0][64 + j] = (_Float16)0.f;
    hbuf[wv][1][j] = (_Float16)0.f; hbuf[wv][1][64 + j] = (_Float16)0.f;

    // per-lane constants: input-proj weight (D_in=1) and fused biases
    float wi0[4], bs0[4], bs1[4];
    #pragma unroll
    for (int q = 0; q < 4; ++q) {
        const int g = q * 64 + j;
        wi0[q] = w_ih0[g];
        bs0[q] = b_ih0[g] + b_hh0[g];
        bs1[q] = b_ih1[g] + b_hh1[g];
    }

    const int b0 = blockIdx.x * 8 + wv * 2;   // this wave's two batch rows

    float c0[2] = {0.f, 0.f}, c1[2] = {0.f, 0.f}, h1r[2] = {0.f, 0.f};

    __syncthreads();   // weights visible to all waves

    const float* xp0 = x + (long)b0 * TSTEPS;
    const float* xp1 = x + (long)(b0 + 1) * TSTEPS;

    // per-lane row bases (compiler hoists all address math out of t-loop)
    int r0base[4], r1base[4];
    #pragma unroll
    for (int q = 0; q < 4; ++q) {
        r0base[q] = (q * 64 + j) * W0P;
        r1base[q] = (q * 64 + j) * W1P;
    }

    for (int t = 0; t < TSTEPS; ++t) {
        const float xv0 = xp0[t];
        const float xv1 = xp1[t];

        // ---------------- layer 0: gates = W_hh0 * h0 ----------------
        float a0[4][2];
        #pragma unroll
        for (int q = 0; q < 4; ++q) { a0[q][0] = bs0[q]; a0[q][1] = bs0[q]; }

        #pragma unroll
        for (int kb = 0; kb < 8; ++kb) {             // 8 f16 per iter
            const h2x4 ha = *(const h2x4*)&hbuf[wv][0][kb * 8];
            const h2x4 hb = *(const h2x4*)&hbuf[wv][1][kb * 8];
            #pragma unroll
            for (int q = 0; q < 4; ++q) {
                const h2x2 wA = *(const h2x2*)&w0s[r0base[q] + kb * 8];
                const h2x2 wB = *(const h2x2*)&w0s[r0base[q] + kb * 8 + 4];
                a0[q][0] = fdot2(wA.a, ha.a, a0[q][0]);
                a0[q][0] = fdot2(wA.b, ha.b, a0[q][0]);
                a0[q][0] = fdot2(wB.a, ha.c, a0[q][0]);
                a0[q][0] = fdot2(wB.b, ha.d, a0[q][0]);
                a0[q][1] = fdot2(wA.a, hb.a, a0[q][1]);
                a0[q][1] = fdot2(wA.b, hb.b, a0[q][1]);
                a0[q][1] = fdot2(wB.a, hb.c, a0[q][1]);
                a0[q][1] = fdot2(wB.b, hb.d, a0[q][1]);
            }
        }

        // epilogue: fold x*w_ih0, activations, c/h update (lane-local)
        float h0n[2];
        {
            float zi = a0[0][0] + xv0 * wi0[0];
            float zf = a0[1][0] + xv0 * wi0[1];
            float zg = a0[2][0] + xv0 * wi0[2];
            float zo = a0[3][0] + xv0 * wi0[3];
            c0[0] = sigf(zf) * c0[0] + sigf(zi) * tanh_fast(zg);
            h0n[0] = sigf(zo) * tanh_fast(c0[0]);
            zi = a0[0][1] + xv1 * wi0[0];
            zf = a0[1][1] + xv1 * wi0[1];
            zg = a0[2][1] + xv1 * wi0[2];
            zo = a0[3][1] + xv1 * wi0[3];
            c0[1] = sigf(zf) * c0[1] + sigf(zi) * tanh_fast(zg);
            h0n[1] = sigf(zo) * tanh_fast(c0[1]);
        }
        hbuf[wv][0][j] = (_Float16)h0n[0];     // h0(t) -> slots 0..63
        hbuf[wv][1][j] = (_Float16)h0n[1];

        // ------------- layer 1: gates = W1 * [h0(t); h1(t-1)] -------------
        float a1[4][2];
        #pragma unroll
        for (int q = 0; q < 4; ++q) { a1[q][0] = bs1[q]; a1[q][1] = bs1[q]; }

        #pragma unroll
        for (int kb = 0; kb < 16; ++kb) {
            const h2x4 ha = *(const h2x4*)&hbuf[wv][0][kb * 8];
            const h2x4 hb = *(const h2x4*)&hbuf[wv][1][kb * 8];
            #pragma unroll
            for (int q = 0; q < 4; ++q) {
                const h2x2 wA = *(const h2x2*)&w1s[r1base[q] + kb * 8];
                const h2x2 wB = *(const h2x2*)&w1s[r1base[q] + kb * 8 + 4];
                a1[q][0] = fdot2(wA.a, ha.a, a1[q][0]);
                a1[q][0] = fdot2(wA.b, ha.b, a1[q][0]);
                a1[q][0] = fdot2(wB.a, ha.c, a1[q][0]);
                a1[q][0] = fdot2(wB.b, ha.d, a1[q][0]);
                a1[q][1] = fdot2(wA.a, hb.a, a1[q][1]);
                a1[q][1] = fdot2(wA.b, hb.b, a1[q][1]);
                a1[q][1] = fdot2(wB.a, hb.c, a1[q][1]);
                a1[q][1] = fdot2(wB.b, hb.d, a1[q][1]);
            }
        }

        #pragma unroll
        for (int b = 0; b < 2; ++b) {
            const float zi = a1[0][b], zf = a1[1][b], zg = a1[2][b], zo = a1[3][b];
            c1[b] = sigf(zf) * c1[b] + sigf(zi) * tanh_fast(zg);
            h1r[b] = sigf(zo) * tanh_fast(c1[b]);
        }
        hbuf[wv][0][64 + j] = (_Float16)h1r[0];   // h1(t) -> slots 64..127
        hbuf[wv][1][64 + j] = (_Float16)h1r[1];
    }

    // ---------------- FC head: out = h1 @ w_fc^T + b_fc ----------------
    const float wfc0 = w_fc[j], wfc1 = w_fc[64 + j], wfc2 = w_fc[128 + j];
    #pragma unroll
    for (int b = 0; b < 2; ++b) {
        float p0 = h1r[b] * wfc0;
        float p1 = h1r[b] * wfc1;
        float p2 = h1r[b] * wfc2;
        #pragma unroll
        for (int off = 32; off > 0; off >>= 1) {
            p0 += __shfl_down(p0, off);
            p1 += __shfl_down(p1, off);
            p2 += __shfl_down(p2, off);
        }
        if (j == 0) {
            float* o = out + (long)(b0 + b) * 3;
            o[0] = p0 + b_fc[0];
            o[1] = p1 + b_fc[1];
            o[2] = p2 + b_fc[2];
        }
    }
}

extern "C" void kernel_launch(void* const* d_in, const int* in_sizes, int n_in,
                              void* d_out, int out_size, void* d_ws, size_t ws_size,
                              hipStream_t stream) {
    const float* xx     = (const float*)d_in[0];
    const float* w_ih0  = (const float*)d_in[1];
    const float* w_hh0  = (const float*)d_in[2];
    const float* b_ih0  = (const float*)d_in[3];
    const float* b_hh0  = (const float*)d_in[4];
    const float* w_ih1  = (const float*)d_in[5];
    const float* w_hh1  = (const float*)d_in[6];
    const float* b_ih1  = (const float*)d_in[7];
    const float* b_hh1  = (const float*)d_in[8];
    const float* w_fc   = (const float*)d_in[9];
    const float* b_fc   = (const float*)d_in[10];
    float* out = (float*)d_out;

    lstm2_fused<<<dim3(256), dim3(256), 0, stream>>>(
        xx, w_ih0, w_hh0, b_ih0, b_hh0,
        w_ih1, w_hh1, b_ih1, b_hh1, w_fc, b_fc, out);
}

// Round 3
// 916.039 us; speedup vs baseline: 2.9312x; 1.5942x over previous
//
#include <hip/hip_runtime.h>

// LSTMClassifier round 2: MFMA restructure.
//   grid = 128 blocks x 256 threads (4 waves). Block = 16 batch rows.
//   Wave w owns units 16w..16w+15; computes 4 N-tiles/layer (one per gate)
//   with mfma_f32_16x16x32_f16. ALL weights live in VGPRs (96 regs/lane).
//   h state double-buffered in LDS [2][16][136] f16; 2 barriers/step.
//   C-frag layout: col=lane&15, row=(lane>>4)*4+i  ->  lane-local c/h update.
//   A/B frag layout: row(/col)=lane&15, k = 8*(lane>>4)+i (8 contiguous).

typedef _Float16 half8   __attribute__((ext_vector_type(8)));
typedef float    float4_t __attribute__((ext_vector_type(4)));

#define T_STEPS 512
#define HPITCH 136        // h row pitch in halfs (128 + 8 pad)

__device__ __forceinline__ float sigf(float z) {
    return 1.0f / (1.0f + __expf(-z));
}
__device__ __forceinline__ float tanh_fast(float z) {
    return 2.0f / (1.0f + __expf(-2.0f * z)) - 1.0f;
}

extern "C" __global__ __launch_bounds__(256, 1)
void lstm2_mfma(const float* __restrict__ x,
                const float* __restrict__ w_ih0, const float* __restrict__ w_hh0,
                const float* __restrict__ b_ih0, const float* __restrict__ b_hh0,
                const float* __restrict__ w_ih1, const float* __restrict__ w_hh1,
                const float* __restrict__ b_ih1, const float* __restrict__ b_hh1,
                const float* __restrict__ w_fc,  const float* __restrict__ b_fc,
                float* __restrict__ out)
{
    __shared__ float    x_lds[T_STEPS][16];    // 32 KB, x[t][row]
    __shared__ _Float16 hbuf[2][16][HPITCH];   // 8.5 KB, [buf][row][h0(0:63)|h1(64:127)]
    __shared__ float    hfin[16][68];          // final h1, f32

    const int tid  = threadIdx.x;
    const int wv   = tid >> 6;          // wave 0..3
    const int lane = tid & 63;
    const int cr   = lane & 15;         // tile col / A row
    const int kg   = lane >> 4;         // k-group 0..3
    const int rb   = kg * 4;            // C-frag row base
    const int b0   = blockIdx.x * 16;   // batch rows of this block

    // ---- stage x[b0..b0+15][t] -> x_lds[t][r] (coalesced reads) ----
    for (int idx = tid; idx < 16 * T_STEPS; idx += 256) {
        const int r = idx >> 9, t = idx & (T_STEPS - 1);
        x_lds[t][r] = x[(long)(b0 + r) * T_STEPS + t];
    }
    // ---- zero h buffers ----
    for (int idx = tid; idx < 2 * 16 * HPITCH; idx += 256)
        ((_Float16*)hbuf)[idx] = (_Float16)0.f;

    // ---- per-lane weight fragments (registers) ----
    const int ucol = wv * 16 + cr;      // this lane's unit 0..63
    half8 w0f[4][2], w1f[4][4];
    float bias0[4], bias1[4], wi0[4];
    #pragma unroll
    for (int g = 0; g < 4; ++g) {
        const int col = g * 64 + ucol;  // gate row in W (PyTorch i,f,g,o order)
        bias0[g] = b_ih0[col] + b_hh0[col];
        bias1[g] = b_ih1[col] + b_hh1[col];
        wi0[g]   = w_ih0[col];
        #pragma unroll
        for (int kt = 0; kt < 2; ++kt) {
            const int k0 = kt * 32 + kg * 8;
            const float* src = w_hh0 + col * 64 + k0;
            #pragma unroll
            for (int i = 0; i < 8; ++i) w0f[g][kt][i] = (_Float16)src[i];
        }
        #pragma unroll
        for (int kt = 0; kt < 4; ++kt) {
            const int k0 = kt * 32 + kg * 8;     // 0..119 within [h0;h1]
            const float* src = (k0 < 64) ? (w_ih1 + col * 64 + k0)
                                         : (w_hh1 + col * 64 + (k0 - 64));
            #pragma unroll
            for (int i = 0; i < 8; ++i) w1f[g][kt][i] = (_Float16)src[i];
        }
    }

    float c0[4] = {0.f,0.f,0.f,0.f}, c1[4] = {0.f,0.f,0.f,0.f};
    float h1v[4] = {0.f,0.f,0.f,0.f};

    __syncthreads();

    for (int t = 0; t < T_STEPS; ++t) {
        const int p = t & 1;

        // ---- phase 1: read h0(t-1), h1(t-1) fragments from buf[p] ----
        half8 a0[2], a1b[2];
        #pragma unroll
        for (int kt = 0; kt < 2; ++kt) {
            a0[kt]  = *(const half8*)&hbuf[p][cr][kt * 32 + kg * 8];
            a1b[kt] = *(const half8*)&hbuf[p][cr][64 + kt * 32 + kg * 8];
        }

        // ---- MFMA: layer0 (full) + layer1 h1-part ----
        float4_t acc0[4], acc1[4];
        #pragma unroll
        for (int g = 0; g < 4; ++g) {
            acc0[g] = (float4_t){bias0[g], bias0[g], bias0[g], bias0[g]};
            acc1[g] = (float4_t){bias1[g], bias1[g], bias1[g], bias1[g]};
        }
        #pragma unroll
        for (int g = 0; g < 4; ++g) {
            acc0[g] = __builtin_amdgcn_mfma_f32_16x16x32_f16(a0[0], w0f[g][0], acc0[g], 0, 0, 0);
            acc0[g] = __builtin_amdgcn_mfma_f32_16x16x32_f16(a0[1], w0f[g][1], acc0[g], 0, 0, 0);
            acc1[g] = __builtin_amdgcn_mfma_f32_16x16x32_f16(a1b[0], w1f[g][2], acc1[g], 0, 0, 0);
            acc1[g] = __builtin_amdgcn_mfma_f32_16x16x32_f16(a1b[1], w1f[g][3], acc1[g], 0, 0, 0);
        }

        // ---- epilogue layer0: +x*w_ih0, activations, c0/h0 update ----
        float h0n[4];
        #pragma unroll
        for (int i = 0; i < 4; ++i) {
            const float xv = x_lds[t][rb + i];
            const float zi = acc0[0][i] + xv * wi0[0];
            const float zf = acc0[1][i] + xv * wi0[1];
            const float zg = acc0[2][i] + xv * wi0[2];
            const float zo = acc0[3][i] + xv * wi0[3];
            c0[i]  = sigf(zf) * c0[i] + sigf(zi) * tanh_fast(zg);
            h0n[i] = sigf(zo) * tanh_fast(c0[i]);
        }
        // write h0(t) -> buf[p^1] cols 0..63   (safe: prev-step barrier B
        // guarantees nobody still reads buf[p^1])
        #pragma unroll
        for (int i = 0; i < 4; ++i)
            hbuf[p ^ 1][rb + i][ucol] = (_Float16)h0n[i];

        __syncthreads();   // barrier A: h0(t) visible

        // ---- layer1 h0-part ----
        half8 a1a[2];
        #pragma unroll
        for (int kt = 0; kt < 2; ++kt)
            a1a[kt] = *(const half8*)&hbuf[p ^ 1][cr][kt * 32 + kg * 8];
        #pragma unroll
        for (int g = 0; g < 4; ++g) {
            acc1[g] = __builtin_amdgcn_mfma_f32_16x16x32_f16(a1a[0], w1f[g][0], acc1[g], 0, 0, 0);
            acc1[g] = __builtin_amdgcn_mfma_f32_16x16x32_f16(a1a[1], w1f[g][1], acc1[g], 0, 0, 0);
        }

        // ---- epilogue layer1 ----
        #pragma unroll
        for (int i = 0; i < 4; ++i) {
            const float zi = acc1[0][i];
            const float zf = acc1[1][i];
            const float zg = acc1[2][i];
            const float zo = acc1[3][i];
            c1[i]  = sigf(zf) * c1[i] + sigf(zi) * tanh_fast(zg);
            h1v[i] = sigf(zo) * tanh_fast(c1[i]);
        }
        #pragma unroll
        for (int i = 0; i < 4; ++i)
            hbuf[p ^ 1][rb + i][64 + ucol] = (_Float16)h1v[i];

        __syncthreads();   // barrier B: h1(t) visible; buf[p] free for reuse
    }

    // ---- FC head ----
    #pragma unroll
    for (int i = 0; i < 4; ++i)
        hfin[rb + i][ucol] = h1v[i];
    __syncthreads();

    if (tid < 48) {
        const int row = tid / 3, cls = tid - row * 3;
        float s = b_fc[cls];
        const float* wr = w_fc + cls * 64;
        #pragma unroll 8
        for (int u = 0; u < 64; ++u) s += hfin[row][u] * wr[u];
        out[(long)(b0 + row) * 3 + cls] = s;
    }
}

extern "C" void kernel_launch(void* const* d_in, const int* in_sizes, int n_in,
                              void* d_out, int out_size, void* d_ws, size_t ws_size,
                              hipStream_t stream) {
    const float* xx     = (const float*)d_in[0];
    const float* w_ih0  = (const float*)d_in[1];
    const float* w_hh0  = (const float*)d_in[2];
    const float* b_ih0  = (const float*)d_in[3];
    const float* b_hh0  = (const float*)d_in[4];
    const float* w_ih1  = (const float*)d_in[5];
    const float* w_hh1  = (const float*)d_in[6];
    const float* b_ih1  = (const float*)d_in[7];
    const float* b_hh1  = (const float*)d_in[8];
    const float* w_fc   = (const float*)d_in[9];
    const float* b_fc   = (const float*)d_in[10];
    float* out = (float*)d_out;

    lstm2_mfma<<<dim3(128), dim3(256), 0, stream>>>(
        xx, w_ih0, w_hh0, b_ih0, b_hh0,
        w_ih1, w_hh1, b_ih1, b_hh1, w_fc, b_fc, out);
}

// Round 4
// 803.341 us; speedup vs baseline: 3.3424x; 1.1403x over previous
//
#include <hip/hip_runtime.h>

// LSTMClassifier round 3: skewed layer pipeline + wave specialization.
//   grid = 128 blocks x 512 threads (8 waves). Block = 16 batch rows.
//   Iter k (k = 0..512):  L0 waves (0-3) compute h0(k) from h0(k-1);
//                         L1 waves (4-7) compute h1(k-1) from h0(k-1), h1(k-2).
//   Both read only buf[p], write only buf[p^1]  ->  ONE barrier per iter.
//   Wave w owns a 16-unit tile of its layer; all weights in VGPRs.
//   C-frag: col=lane&15, row=(lane>>4)*4+i  ->  lane-local c/h update.
//   hbuf pitch 132 halfs (66 dwords = 2 mod 32): conflict-free b16 writes.

typedef _Float16 half8    __attribute__((ext_vector_type(8)));
typedef float    float4_t __attribute__((ext_vector_type(4)));

#define T_STEPS 512
#define HP 132            // h row pitch in halfs

__device__ __forceinline__ float sigf(float z) {
    return 1.0f / (1.0f + __expf(-z));
}
__device__ __forceinline__ float tanh_fast(float z) {
    return 2.0f / (1.0f + __expf(-2.0f * z)) - 1.0f;
}

extern "C" __global__ __launch_bounds__(512, 1)
void lstm2_mfma(const float* __restrict__ x,
                const float* __restrict__ w_ih0, const float* __restrict__ w_hh0,
                const float* __restrict__ b_ih0, const float* __restrict__ b_hh0,
                const float* __restrict__ w_ih1, const float* __restrict__ w_hh1,
                const float* __restrict__ b_ih1, const float* __restrict__ b_hh1,
                const float* __restrict__ w_fc,  const float* __restrict__ b_fc,
                float* __restrict__ out)
{
    __shared__ float    x_lds[T_STEPS][16];    // 32 KB
    __shared__ _Float16 hbuf[2][16][HP];       // 8.25 KB [buf][row][h0|h1]
    __shared__ float    hfin[16][68];          // final h1

    const int tid  = threadIdx.x;
    const int wv   = tid >> 6;          // wave 0..7
    const int lane = tid & 63;
    const int cr   = lane & 15;         // tile col (batch row of A) / C col
    const int kg   = lane >> 4;         // k-group 0..3
    const int rb   = kg * 4;            // C-frag row base
    const int b0   = blockIdx.x * 16;
    const bool isL0 = (wv < 4);
    const int u    = wv & 3;            // unit tile 0..3
    const int ucol = u * 16 + cr;       // this lane's unit 0..63

    // ---- stage x[b0..b0+15][t] -> x_lds[t][r] ----
    for (int idx = tid; idx < 16 * T_STEPS; idx += 512) {
        const int r = idx >> 9, t = idx & (T_STEPS - 1);
        x_lds[t][r] = x[(long)(b0 + r) * T_STEPS + t];
    }
    // ---- zero both h buffers (h0(-1) = 0, h1(-1) = 0) ----
    for (int idx = tid; idx < 2 * 16 * HP; idx += 512)
        ((_Float16*)hbuf)[idx] = (_Float16)0.f;

    // ---- per-lane weight fragments (registers), layer-specialized ----
    half8 wf[4][4];                 // L0 uses [g][0..1]; L1 uses [g][0..3]
    float bias[4], wi0g[4];
    #pragma unroll
    for (int g = 0; g < 4; ++g) {
        const int col = g * 64 + ucol;     // gate row (PyTorch i,f,g,o)
        if (isL0) {
            bias[g] = b_ih0[col] + b_hh0[col];
            wi0g[g] = w_ih0[col];
            #pragma unroll
            for (int kt = 0; kt < 2; ++kt) {
                const float* src = w_hh0 + col * 64 + kt * 32 + kg * 8;
                #pragma unroll
                for (int i = 0; i < 8; ++i) wf[g][kt][i] = (_Float16)src[i];
            }
        } else {
            bias[g] = b_ih1[col] + b_hh1[col];
            #pragma unroll
            for (int kt = 0; kt < 4; ++kt) {
                const int k0 = kt * 32 + kg * 8;   // 0..119 in [h0;h1]
                const float* src = (k0 < 64) ? (w_ih1 + col * 64 + k0)
                                             : (w_hh1 + col * 64 + (k0 - 64));
                #pragma unroll
                for (int i = 0; i < 8; ++i) wf[g][kt][i] = (_Float16)src[i];
            }
        }
    }

    float cc[4] = {0.f,0.f,0.f,0.f};    // c state (c0 for L0 waves, c1 for L1)
    float hv[4] = {0.f,0.f,0.f,0.f};    // last h written

    __syncthreads();

    for (int k = 0; k <= T_STEPS; ++k) {
        const int p = k & 1;            // read buf[p], write buf[p^1]

        if (isL0) {
            if (k < T_STEPS) {
                half8 a[2];
                a[0] = *(const half8*)&hbuf[p][cr][kg * 8];
                a[1] = *(const half8*)&hbuf[p][cr][32 + kg * 8];
                float4_t acc[4];
                #pragma unroll
                for (int g = 0; g < 4; ++g)
                    acc[g] = (float4_t){bias[g], bias[g], bias[g], bias[g]};
                #pragma unroll
                for (int g = 0; g < 4; ++g) {
                    acc[g] = __builtin_amdgcn_mfma_f32_16x16x32_f16(a[0], wf[g][0], acc[g], 0, 0, 0);
                    acc[g] = __builtin_amdgcn_mfma_f32_16x16x32_f16(a[1], wf[g][1], acc[g], 0, 0, 0);
                }
                #pragma unroll
                for (int i = 0; i < 4; ++i) {
                    const float xv = x_lds[k][rb + i];
                    const float zi = acc[0][i] + xv * wi0g[0];
                    const float zf = acc[1][i] + xv * wi0g[1];
                    const float zg = acc[2][i] + xv * wi0g[2];
                    const float zo = acc[3][i] + xv * wi0g[3];
                    cc[i] = sigf(zf) * cc[i] + sigf(zi) * tanh_fast(zg);
                    hv[i] = sigf(zo) * tanh_fast(cc[i]);
                    hbuf[p ^ 1][rb + i][ucol] = (_Float16)hv[i];
                }
            }
        } else {
            if (k >= 1) {
                half8 a[4];
                a[0] = *(const half8*)&hbuf[p][cr][kg * 8];          // h0(k-1)
                a[1] = *(const half8*)&hbuf[p][cr][32 + kg * 8];
                a[2] = *(const half8*)&hbuf[p][cr][64 + kg * 8];     // h1(k-2)
                a[3] = *(const half8*)&hbuf[p][cr][96 + kg * 8];
                float4_t acc[4];
                #pragma unroll
                for (int g = 0; g < 4; ++g)
                    acc[g] = (float4_t){bias[g], bias[g], bias[g], bias[g]};
                #pragma unroll
                for (int g = 0; g < 4; ++g) {
                    #pragma unroll
                    for (int kt = 0; kt < 4; ++kt)
                        acc[g] = __builtin_amdgcn_mfma_f32_16x16x32_f16(a[kt], wf[g][kt], acc[g], 0, 0, 0);
                }
                #pragma unroll
                for (int i = 0; i < 4; ++i) {
                    const float zi = acc[0][i];
                    const float zf = acc[1][i];
                    const float zg = acc[2][i];
                    const float zo = acc[3][i];
                    cc[i] = sigf(zf) * cc[i] + sigf(zi) * tanh_fast(zg);
                    hv[i] = sigf(zo) * tanh_fast(cc[i]);
                    hbuf[p ^ 1][rb + i][64 + ucol] = (_Float16)hv[i];
                }
            }
        }

        __syncthreads();    // writes of iter k visible to iter k+1
    }

    // ---- FC head: h_last = h1(511), held by L1 waves ----
    if (!isL0) {
        #pragma unroll
        for (int i = 0; i < 4; ++i)
            hfin[rb + i][ucol] = hv[i];
    }
    __syncthreads();

    if (tid < 48) {
        const int row = tid / 3, cls = tid - row * 3;
        float s = b_fc[cls];
        const float* wr = w_fc + cls * 64;
        #pragma unroll 8
        for (int uu = 0; uu < 64; ++uu) s += hfin[row][uu] * wr[uu];
        out[(long)(b0 + row) * 3 + cls] = s;
    }
}

extern "C" void kernel_launch(void* const* d_in, const int* in_sizes, int n_in,
                              void* d_out, int out_size, void* d_ws, size_t ws_size,
                              hipStream_t stream) {
    const float* xx     = (const float*)d_in[0];
    const float* w_ih0  = (const float*)d_in[1];
    const float* w_hh0  = (const float*)d_in[2];
    const float* b_ih0  = (const float*)d_in[3];
    const float* b_hh0  = (const float*)d_in[4];
    const float* w_ih1  = (const float*)d_in[5];
    const float* w_hh1  = (const float*)d_in[6];
    const float* b_ih1  = (const float*)d_in[7];
    const float* b_hh1  = (const float*)d_in[8];
    const float* w_fc   = (const float*)d_in[9];
    const float* b_fc   = (const float*)d_in[10];
    float* out = (float*)d_out;

    lstm2_mfma<<<dim3(128), dim3(512), 0, stream>>>(
        xx, w_ih0, w_hh0, b_ih0, b_hh0,
        w_ih1, w_hh1, b_ih1, b_hh1, w_fc, b_fc, out);
}

// Round 5
// 785.566 us; speedup vs baseline: 3.4181x; 1.0226x over previous
//
#include <hip/hip_runtime.h>

// LSTMClassifier round 4: skew-2 pipeline + cross-barrier prefetch + swizzled h-bufs.
//   grid = 128 blocks x 512 threads (8 waves). Block = 16 batch rows.
//   Iter k (0..513):
//     L0 waves (0-3): h0(k) = f(h0(k-1))                      [k <= 511]
//     L1 waves (4-7): h1(k-2) = f(h0(k-2), h1(k-3))           [k >= 2]
//   h0(k-2) is consumed from REGISTERS prefetched at iter k-1 (published two
//   barriers ago) -> L1's post-barrier chain has no LDS-read latency.
//   h buffers: triple-buffered slots, XOR-rotated 8-half blocks
//   (half = row*64 + ((kb+row)&7)*8 + lo): b128 gathers at the 8/bank floor,
//   b16 scatter writes <=2-way. One barrier per iter.

typedef _Float16 half8    __attribute__((ext_vector_type(8)));
typedef float    float4_t __attribute__((ext_vector_type(4)));

#define T_STEPS 512

__device__ __forceinline__ int hoff(int slot, int row, int kb, int lo) {
    return slot * 1024 + row * 64 + (((kb + row) & 7) << 3) + lo;
}

__device__ __forceinline__ float sigf(float z) {
    return 1.0f / (1.0f + __expf(-z));
}
__device__ __forceinline__ float tanh_fast(float z) {
    return 2.0f / (1.0f + __expf(-2.0f * z)) - 1.0f;
}

extern "C" __global__ __launch_bounds__(512, 1)
void lstm2_mfma(const float* __restrict__ x,
                const float* __restrict__ w_ih0, const float* __restrict__ w_hh0,
                const float* __restrict__ b_ih0, const float* __restrict__ b_hh0,
                const float* __restrict__ w_ih1, const float* __restrict__ w_hh1,
                const float* __restrict__ b_ih1, const float* __restrict__ b_hh1,
                const float* __restrict__ w_fc,  const float* __restrict__ b_fc,
                float* __restrict__ out)
{
    __shared__ float    x_lds[T_STEPS][16];    // 32 KB
    __shared__ _Float16 bufA[3 * 1024];        // h0 slots (t % 3)
    __shared__ _Float16 bufB[3 * 1024];        // h1 slots (t % 3)
    __shared__ float    hfin[16][68];

    const int tid  = threadIdx.x;
    const int wv   = tid >> 6;          // wave 0..7
    const int lane = tid & 63;
    const int cr   = lane & 15;         // A-row (batch) / C-col (unit)
    const int kg   = lane >> 4;         // k-group 0..3
    const int rb   = kg * 4;            // C-frag row base
    const int b0   = blockIdx.x * 16;
    const bool isL0 = (wv < 4);
    const int u    = wv & 3;            // unit tile 0..3
    const int ucol = u * 16 + cr;       // this lane's unit 0..63
    const int wkb  = 2 * u + (cr >> 3); // write-side 8-half block index

    // ---- stage x[b0..b0+15][t] -> x_lds[t][r] ----
    for (int idx = tid; idx < 16 * T_STEPS; idx += 512) {
        const int r = idx >> 9, t = idx & (T_STEPS - 1);
        x_lds[t][r] = x[(long)(b0 + r) * T_STEPS + t];
    }
    // ---- zero all h slots (h0(-1)=0, h1(-1)=0 live in slot 2) ----
    for (int idx = tid; idx < 3 * 1024; idx += 512) {
        bufA[idx] = (_Float16)0.f;
        bufB[idx] = (_Float16)0.f;
    }

    // ---- per-lane weight fragments (registers), layer-specialized ----
    half8 wf[4][4];                 // L0 uses [g][0..1]; L1 uses [g][0..3]
    float bias[4], wi0g[4];
    #pragma unroll
    for (int g = 0; g < 4; ++g) {
        const int col = g * 64 + ucol;     // gate row (PyTorch i,f,g,o)
        if (isL0) {
            bias[g] = b_ih0[col] + b_hh0[col];
            wi0g[g] = w_ih0[col];
            #pragma unroll
            for (int kt = 0; kt < 2; ++kt) {
                const float* src = w_hh0 + col * 64 + kt * 32 + kg * 8;
                #pragma unroll
                for (int i = 0; i < 8; ++i) wf[g][kt][i] = (_Float16)src[i];
            }
        } else {
            bias[g] = b_ih1[col] + b_hh1[col];
            #pragma unroll
            for (int kt = 0; kt < 4; ++kt) {
                const int k0 = kt * 32 + kg * 8;   // 0..119 in [h0;h1]
                const float* src = (k0 < 64) ? (w_ih1 + col * 64 + k0)
                                             : (w_hh1 + col * 64 + (k0 - 64));
                #pragma unroll
                for (int i = 0; i < 8; ++i) wf[g][kt][i] = (_Float16)src[i];
            }
        }
    }

    float cc[4] = {0.f,0.f,0.f,0.f};
    float hv[4] = {0.f,0.f,0.f,0.f};
    half8 ca0 = {}, ca1 = {};           // L1: current h0 frags (prefetched)

    __syncthreads();

    for (int k = 0; k <= T_STEPS + 1; ++k) {
        if (isL0) {
            if (k < T_STEPS) {
                const int rs = (k + 2) % 3;            // slot of h0(k-1)
                const half8 a0 = *(const half8*)&bufA[hoff(rs, cr, kg,     0)];
                const half8 a1 = *(const half8*)&bufA[hoff(rs, cr, 4 + kg, 0)];
                const float4_t xq = *(const float4_t*)&x_lds[k][rb];
                float4_t acc[4];
                #pragma unroll
                for (int g = 0; g < 4; ++g)
                    acc[g] = (float4_t){bias[g], bias[g], bias[g], bias[g]};
                #pragma unroll
                for (int g = 0; g < 4; ++g) {
                    acc[g] = __builtin_amdgcn_mfma_f32_16x16x32_f16(a0, wf[g][0], acc[g], 0, 0, 0);
                    acc[g] = __builtin_amdgcn_mfma_f32_16x16x32_f16(a1, wf[g][1], acc[g], 0, 0, 0);
                }
                const int ws = k % 3;                  // slot of h0(k)
                #pragma unroll
                for (int i = 0; i < 4; ++i) {
                    const float xv = xq[i];
                    const float zi = acc[0][i] + xv * wi0g[0];
                    const float zf = acc[1][i] + xv * wi0g[1];
                    const float zg = acc[2][i] + xv * wi0g[2];
                    const float zo = acc[3][i] + xv * wi0g[3];
                    cc[i] = sigf(zf) * cc[i] + sigf(zi) * tanh_fast(zg);
                    hv[i] = sigf(zo) * tanh_fast(cc[i]);
                    bufA[hoff(ws, rb + i, wkb, cr & 7)] = (_Float16)hv[i];
                }
            }
        } else {
            // prefetch h0(k-1) for NEXT iter's compute (published at barrier k-1)
            half8 n0 = {}, n1 = {};
            if (k >= 1 && k <= T_STEPS) {
                const int ps = (k + 2) % 3;            // slot of h0(k-1)
                n0 = *(const half8*)&bufA[hoff(ps, cr, kg,     0)];
                n1 = *(const half8*)&bufA[hoff(ps, cr, 4 + kg, 0)];
            }
            if (k >= 2) {
                const int hs = k % 3;                  // slot of h1(k-3)
                const half8 b0h = *(const half8*)&bufB[hoff(hs, cr, kg,     0)];
                const half8 b1h = *(const half8*)&bufB[hoff(hs, cr, 4 + kg, 0)];
                float4_t acc[4];
                #pragma unroll
                for (int g = 0; g < 4; ++g)
                    acc[g] = (float4_t){bias[g], bias[g], bias[g], bias[g]};
                #pragma unroll
                for (int g = 0; g < 4; ++g) {          // h0 part: registers only
                    acc[g] = __builtin_amdgcn_mfma_f32_16x16x32_f16(ca0, wf[g][0], acc[g], 0, 0, 0);
                    acc[g] = __builtin_amdgcn_mfma_f32_16x16x32_f16(ca1, wf[g][1], acc[g], 0, 0, 0);
                }
                #pragma unroll
                for (int g = 0; g < 4; ++g) {          // h1 part: read hides here
                    acc[g] = __builtin_amdgcn_mfma_f32_16x16x32_f16(b0h, wf[g][2], acc[g], 0, 0, 0);
                    acc[g] = __builtin_amdgcn_mfma_f32_16x16x32_f16(b1h, wf[g][3], acc[g], 0, 0, 0);
                }
                const int ws = (k + 1) % 3;            // slot of h1(k-2)
                #pragma unroll
                for (int i = 0; i < 4; ++i) {
                    const float zi = acc[0][i];
                    const float zf = acc[1][i];
                    const float zg = acc[2][i];
                    const float zo = acc[3][i];
                    cc[i] = sigf(zf) * cc[i] + sigf(zi) * tanh_fast(zg);
                    hv[i] = sigf(zo) * tanh_fast(cc[i]);
                    bufB[hoff(ws, rb + i, wkb, cr & 7)] = (_Float16)hv[i];
                }
            }
            ca0 = n0; ca1 = n1;                        // rotate prefetch regs
        }
        __syncthreads();
    }

    // ---- FC head: h_last = h1(511), held by L1 waves ----
    if (!isL0) {
        #pragma unroll
        for (int i = 0; i < 4; ++i)
            hfin[rb + i][ucol] = hv[i];
    }
    __syncthreads();

    if (tid < 48) {
        const int row = tid / 3, cls = tid - row * 3;
        float s = b_fc[cls];
        const float* wr = w_fc + cls * 64;
        #pragma unroll 8
        for (int uu = 0; uu < 64; ++uu) s += hfin[row][uu] * wr[uu];
        out[(long)(b0 + row) * 3 + cls] = s;
    }
}

extern "C" void kernel_launch(void* const* d_in, const int* in_sizes, int n_in,
                              void* d_out, int out_size, void* d_ws, size_t ws_size,
                              hipStream_t stream) {
    const float* xx     = (const float*)d_in[0];
    const float* w_ih0  = (const float*)d_in[1];
    const float* w_hh0  = (const float*)d_in[2];
    const float* b_ih0  = (const float*)d_in[3];
    const float* b_hh0  = (const float*)d_in[4];
    const float* w_ih1  = (const float*)d_in[5];
    const float* w_hh1  = (const float*)d_in[6];
    const float* b_ih1  = (const float*)d_in[7];
    const float* b_hh1  = (const float*)d_in[8];
    const float* w_fc   = (const float*)d_in[9];
    const float* b_fc   = (const float*)d_in[10];
    float* out = (float*)d_out;

    lstm2_mfma<<<dim3(128), dim3(512), 0, stream>>>(
        xx, w_ih0, w_hh0, b_ih0, b_hh0,
        w_ih1, w_hh1, b_ih1, b_hh1, w_fc, b_fc, out);
}

// Round 6
// 538.965 us; speedup vs baseline: 4.9820x; 1.4575x over previous
//
#include <hip/hip_runtime.h>

// LSTMClassifier round 5: issue-count attack.
//   grid = 128 blocks x 1024 threads (16 waves). Block = 16 batch rows.
//   Skew-2 pipeline (round 4) kept:
//     L0 waves (0-7):  h0(k)   = f(h0(k-1))            [k <= 511]
//     L1 waves (8-15): h1(k-2) = f(h0(k-2), h1(k-3))   [k >= 2]
//   NEW: wave pairs (u, ph) compute the same MFMA tiles redundantly but
//   split the 4 C-rows 2/2 -> per-wave epilogue chain halves; 4 waves/SIMD.
//   NEW: exp2/rcp builtins with log2e pre-scaled into weights/bias:
//     sigmoid(z) = rcp(1 + exp2(z*(-log2e)))  [3 ops, no precise-divide seq]
//     tanh(z)    = 2*rcp(1 + exp2(z*(-2log2e))) - 1
//   NEW: s_setprio(1) for L0 waves (critical path; L1 has 2-iter slack).

typedef _Float16 half8    __attribute__((ext_vector_type(8)));
typedef float    float4_t __attribute__((ext_vector_type(4)));
typedef float    float2_t __attribute__((ext_vector_type(2)));

#define T_STEPS 512
#define SIG_K  (-1.442695040888963f)    // -log2(e)
#define TANH_K (-2.885390081777927f)    // -2*log2(e)

__device__ __forceinline__ int hoff(int slot, int row, int kb, int lo) {
    return slot * 1024 + row * 64 + (((kb + row) & 7) << 3) + lo;
}
// zp is pre-scaled: sig2(z*SIG_K) == sigmoid(z); 2*sig2(z*TANH_K)-1 == tanh(z)
__device__ __forceinline__ float sig2(float zp) {
    return __builtin_amdgcn_rcpf(1.0f + __builtin_amdgcn_exp2f(zp));
}

extern "C" __global__ __launch_bounds__(1024)
void lstm2_mfma(const float* __restrict__ x,
                const float* __restrict__ w_ih0, const float* __restrict__ w_hh0,
                const float* __restrict__ b_ih0, const float* __restrict__ b_hh0,
                const float* __restrict__ w_ih1, const float* __restrict__ w_hh1,
                const float* __restrict__ b_ih1, const float* __restrict__ b_hh1,
                const float* __restrict__ w_fc,  const float* __restrict__ b_fc,
                float* __restrict__ out)
{
    __shared__ float    x_lds[T_STEPS][16];    // 32 KB
    __shared__ _Float16 bufA[3 * 1024];        // h0 slots (t % 3)
    __shared__ _Float16 bufB[3 * 1024];        // h1 slots (t % 3)
    __shared__ float    hfin[16][68];

    const int tid  = threadIdx.x;
    const int wv   = tid >> 6;          // wave 0..15
    const int lane = tid & 63;
    const int cr   = lane & 15;         // A-row (batch) / C-col (unit)
    const int kg   = lane >> 4;         // k-group 0..3
    const int rb   = kg * 4;            // C-frag row base
    const int b0   = blockIdx.x * 16;
    const bool isL0 = (wv < 8);
    const int u    = (wv >> 1) & 3;     // unit tile 0..3
    const int ph   = __builtin_amdgcn_readfirstlane(wv & 1);  // row-pair half
    const int ucol = u * 16 + cr;       // this lane's unit 0..63
    const int wkb  = 2 * u + (cr >> 3); // write-side 8-half block index

    // ---- stage x[b0..b0+15][t] -> x_lds[t][r] ----
    for (int idx = tid; idx < 16 * T_STEPS; idx += 1024) {
        const int r = idx >> 9, t = idx & (T_STEPS - 1);
        x_lds[t][r] = x[(long)(b0 + r) * T_STEPS + t];
    }
    for (int idx = tid; idx < 3 * 1024; idx += 1024) {
        bufA[idx] = (_Float16)0.f;
        bufB[idx] = (_Float16)0.f;
    }

    // ---- per-lane weight fragments (registers), pre-scaled by -log2e ----
    half8 wf[4][4];                 // L0 uses [g][0..1]; L1 uses [g][0..3]
    float bias[4], wi0g[4];
    #pragma unroll
    for (int g = 0; g < 4; ++g) {
        const float sc = (g == 2) ? TANH_K : SIG_K;   // gate 2 = g (tanh)
        const int col = g * 64 + ucol;                // PyTorch i,f,g,o
        if (isL0) {
            bias[g] = (b_ih0[col] + b_hh0[col]) * sc;
            wi0g[g] = w_ih0[col] * sc;
            #pragma unroll
            for (int kt = 0; kt < 2; ++kt) {
                const float* src = w_hh0 + col * 64 + kt * 32 + kg * 8;
                #pragma unroll
                for (int i = 0; i < 8; ++i) wf[g][kt][i] = (_Float16)(src[i] * sc);
            }
        } else {
            bias[g] = (b_ih1[col] + b_hh1[col]) * sc;
            #pragma unroll
            for (int kt = 0; kt < 4; ++kt) {
                const int k0 = kt * 32 + kg * 8;   // 0..119 in [h0;h1]
                const float* src = (k0 < 64) ? (w_ih1 + col * 64 + k0)
                                             : (w_hh1 + col * 64 + (k0 - 64));
                #pragma unroll
                for (int i = 0; i < 8; ++i) wf[g][kt][i] = (_Float16)(src[i] * sc);
            }
        }
    }

    const float4_t zero4 = {0.f, 0.f, 0.f, 0.f};
    float cc[2] = {0.f, 0.f};
    float hv[2] = {0.f, 0.f};
    half8 ca0 = {}, ca1 = {};           // L1: h0 frags prefetched last iter

    if (isL0) __builtin_amdgcn_s_setprio(1);   // L0 = critical path

    __syncthreads();

    for (int k = 0; k <= T_STEPS + 1; ++k) {
        if (isL0) {
            if (k < T_STEPS) {
                const int rs = (k + 2) % 3;            // slot of h0(k-1)
                const half8 a0 = *(const half8*)&bufA[hoff(rs, cr, kg,     0)];
                const half8 a1 = *(const half8*)&bufA[hoff(rs, cr, 4 + kg, 0)];
                const float2_t xq = *(const float2_t*)&x_lds[k][rb + 2 * ph];
                float4_t acc[4];
                #pragma unroll
                for (int g = 0; g < 4; ++g) {
                    acc[g] = __builtin_amdgcn_mfma_f32_16x16x32_f16(a0, wf[g][0], zero4, 0, 0, 0);
                    acc[g] = __builtin_amdgcn_mfma_f32_16x16x32_f16(a1, wf[g][1], acc[g], 0, 0, 0);
                }
                float z[4][2];
                if (ph == 0) {
                    #pragma unroll
                    for (int g = 0; g < 4; ++g) { z[g][0] = acc[g][0]; z[g][1] = acc[g][1]; }
                } else {
                    #pragma unroll
                    for (int g = 0; g < 4; ++g) { z[g][0] = acc[g][2]; z[g][1] = acc[g][3]; }
                }
                const int ws = k % 3;                  // slot of h0(k)
                #pragma unroll
                for (int ii = 0; ii < 2; ++ii) {
                    const float xv = xq[ii];
                    const float zi = fmaf(xv, wi0g[0], z[0][ii] + bias[0]);
                    const float zf = fmaf(xv, wi0g[1], z[1][ii] + bias[1]);
                    const float zg = fmaf(xv, wi0g[2], z[2][ii] + bias[2]);
                    const float zo = fmaf(xv, wi0g[3], z[3][ii] + bias[3]);
                    const float ri = sig2(zi), rf = sig2(zf);
                    const float ro = sig2(zo), rg = sig2(zg);
                    const float gg = fmaf(2.f, rg, -1.f);
                    cc[ii] = fmaf(rf, cc[ii], ri * gg);
                    const float th = fmaf(2.f, sig2(cc[ii] * TANH_K), -1.f);
                    hv[ii] = ro * th;
                    bufA[hoff(ws, rb + 2 * ph + ii, wkb, cr & 7)] = (_Float16)hv[ii];
                }
            }
        } else {
            // prefetch h0(k-1) for NEXT iter (published at barrier k-1)
            half8 n0 = {}, n1 = {};
            if (k >= 1 && k <= T_STEPS) {
                const int ps = (k + 2) % 3;            // slot of h0(k-1)
                n0 = *(const half8*)&bufA[hoff(ps, cr, kg,     0)];
                n1 = *(const half8*)&bufA[hoff(ps, cr, 4 + kg, 0)];
            }
            if (k >= 2) {
                const int hs = k % 3;                  // slot of h1(k-3)
                const half8 bh0 = *(const half8*)&bufB[hoff(hs, cr, kg,     0)];
                const half8 bh1 = *(const half8*)&bufB[hoff(hs, cr, 4 + kg, 0)];
                float4_t acc[4];
                #pragma unroll
                for (int g = 0; g < 4; ++g) {
                    acc[g] = __builtin_amdgcn_mfma_f32_16x16x32_f16(ca0, wf[g][0], zero4, 0, 0, 0);
                    acc[g] = __builtin_amdgcn_mfma_f32_16x16x32_f16(ca1, wf[g][1], acc[g], 0, 0, 0);
                    acc[g] = __builtin_amdgcn_mfma_f32_16x16x32_f16(bh0, wf[g][2], acc[g], 0, 0, 0);
                    acc[g] = __builtin_amdgcn_mfma_f32_16x16x32_f16(bh1, wf[g][3], acc[g], 0, 0, 0);
                }
                float z[4][2];
                if (ph == 0) {
                    #pragma unroll
                    for (int g = 0; g < 4; ++g) { z[g][0] = acc[g][0]; z[g][1] = acc[g][1]; }
                } else {
                    #pragma unroll
                    for (int g = 0; g < 4; ++g) { z[g][0] = acc[g][2]; z[g][1] = acc[g][3]; }
                }
                const int ws = (k + 1) % 3;            // slot of h1(k-2)
                #pragma unroll
                for (int ii = 0; ii < 2; ++ii) {
                    const float zi = z[0][ii] + bias[0];
                    const float zf = z[1][ii] + bias[1];
                    const float zg = z[2][ii] + bias[2];
                    const float zo = z[3][ii] + bias[3];
                    const float ri = sig2(zi), rf = sig2(zf);
                    const float ro = sig2(zo), rg = sig2(zg);
                    const float gg = fmaf(2.f, rg, -1.f);
                    cc[ii] = fmaf(rf, cc[ii], ri * gg);
                    const float th = fmaf(2.f, sig2(cc[ii] * TANH_K), -1.f);
                    hv[ii] = ro * th;
                    bufB[hoff(ws, rb + 2 * ph + ii, wkb, cr & 7)] = (_Float16)hv[ii];
                }
            }
            ca0 = n0; ca1 = n1;
        }
        __syncthreads();
    }

    // ---- FC head: h_last = h1(511), held by L1 waves ----
    if (!isL0) {
        hfin[rb + 2 * ph + 0][ucol] = hv[0];
        hfin[rb + 2 * ph + 1][ucol] = hv[1];
    }
    __syncthreads();

    if (tid < 48) {
        const int row = tid / 3, cls = tid - row * 3;
        float s = b_fc[cls];
        const float* wr = w_fc + cls * 64;
        #pragma unroll 8
        for (int uu = 0; uu < 64; ++uu) s += hfin[row][uu] * wr[uu];
        out[(long)(b0 + row) * 3 + cls] = s;
    }
}

extern "C" void kernel_launch(void* const* d_in, const int* in_sizes, int n_in,
                              void* d_out, int out_size, void* d_ws, size_t ws_size,
                              hipStream_t stream) {
    const float* xx     = (const float*)d_in[0];
    const float* w_ih0  = (const float*)d_in[1];
    const float* w_hh0  = (const float*)d_in[2];
    const float* b_ih0  = (const float*)d_in[3];
    const float* b_hh0  = (const float*)d_in[4];
    const float* w_ih1  = (const float*)d_in[5];
    const float* w_hh1  = (const float*)d_in[6];
    const float* b_ih1  = (const float*)d_in[7];
    const float* b_hh1  = (const float*)d_in[8];
    const float* w_fc   = (const float*)d_in[9];
    const float* b_fc   = (const float*)d_in[10];
    float* out = (float*)d_out;

    lstm2_mfma<<<dim3(128), dim3(1024), 0, stream>>>(
        xx, w_ih0, w_hh0, b_ih0, b_hh0,
        w_ih1, w_hh1, b_ih1, b_hh1, w_fc, b_fc, out);
}